// Round 5
// baseline (184.634 us; speedup 1.0000x reference)
//
#include <hip/hip_runtime.h>

#define NODELEN 10
#define DEG 32
#define NPB 64          // nodes per block in hop2 (256 threads, 4 lanes/node)

// fp8 tables: one row per node, 10 fp8 bytes used, padded to 16 B so each
// gather is a single global_load_dwordx4; table = 200k x 16 B = 3.2 MB,
// fits per-XCD 4 MiB L2 -> gathers are L2 hits after warm-up.

#if defined(__has_builtin)
#if __has_builtin(__builtin_amdgcn_cvt_pk_f32_fp8)
#define USE_HW_FP8_DECODE 1
#endif
#endif

typedef float floatx2 __attribute__((ext_vector_type(2)));

__device__ __forceinline__ float fp8_to_f32_sw(unsigned b) {
    unsigned s = (b & 0x80u) << 24;
    unsigned e = (b >> 3) & 0xFu;
    unsigned m = b & 0x7u;
    float fn = __uint_as_float(s | ((e + 120u) << 23) | (m << 20));
    float fs = __uint_as_float(s | __float_as_uint((float)m * 0.001953125f));
    return e ? fn : fs;
}

__device__ __forceinline__ void dacc(float& a, float& b, unsigned w, int hi) {
#if defined(USE_HW_FP8_DECODE)
    floatx2 f = hi ? __builtin_amdgcn_cvt_pk_f32_fp8(w, true)
                   : __builtin_amdgcn_cvt_pk_f32_fp8(w, false);
    a += f.x; b += f.y;
#else
    unsigned p = hi ? (w >> 16) : w;
    a += fp8_to_f32_sw(p & 0xFFu);
    b += fp8_to_f32_sw((p >> 8) & 0xFFu);
#endif
}

__device__ __forceinline__ unsigned fp8_encode(float f) {
    unsigned u = __float_as_uint(f);
    unsigned s = u >> 31;
    float a = fabsf(f);
    if (a < 0.015625f) {
        int mi = __float2int_rn(a * 512.0f);
        return (s << 7) | (unsigned)mi;
    }
    int e = (int)((u >> 23) & 0xFFu) - 127;
    unsigned mant = u & 0x7FFFFFu;
    unsigned r = mant + 0x7FFFFu + ((mant >> 20) & 1u);
    mant = r >> 20;
    if (mant == 8u) { mant = 0u; e += 1; }
    return (s << 7) | ((unsigned)(e + 7) << 3) | mant;
}

__device__ __forceinline__ int4 pack_row_fp8(const float* v) {
    unsigned b[NODELEN];
#pragma unroll
    for (int k = 0; k < NODELEN; ++k) b[k] = fp8_encode(v[k]);
    int4 p;
    p.x = (int)(b[0] | (b[1] << 8) | (b[2] << 16) | (b[3] << 24));
    p.y = (int)(b[4] | (b[5] << 8) | (b[6] << 16) | (b[7] << 24));
    p.z = (int)(b[8] | (b[9] << 8));
    p.w = 0;
    return p;
}

__device__ __forceinline__ void row_acc(float* s, int4 p) {
    unsigned w0 = (unsigned)p.x, w1 = (unsigned)p.y, w2 = (unsigned)p.z;
    dacc(s[0], s[1], w0, 0);
    dacc(s[2], s[3], w0, 1);
    dacc(s[4], s[5], w1, 0);
    dacc(s[6], s[7], w1, 1);
    dacc(s[8], s[9], w2, 0);
}

// gather 8 rows (all loads issued before any decode -> one latency window).
// Requires VGPR headroom (launch_bounds min-waves=4 -> ~128 VGPR cap) or the
// allocator serializes this into 2-at-a-time batches (round-4 lesson: VGPR=36).
__device__ __forceinline__ void gather8_acc(float* s, const int4* __restrict__ tab,
                                            int4 n0, int4 n1) {
    int4 r0 = tab[n0.x];
    int4 r1 = tab[n0.y];
    int4 r2 = tab[n0.z];
    int4 r3 = tab[n0.w];
    int4 r4 = tab[n1.x];
    int4 r5 = tab[n1.y];
    int4 r6 = tab[n1.z];
    int4 r7 = tab[n1.w];
    row_acc(s, r0);
    row_acc(s, r1);
    row_acc(s, r2);
    row_acc(s, r3);
    row_acc(s, r4);
    row_acc(s, r5);
    row_acc(s, r6);
    row_acc(s, r7);
}

// ---------------------------------------------------------------------------
// Kernel 0: features (fp32 [N][10]) -> fp8 table ([N] x 16B)
// ---------------------------------------------------------------------------
__global__ __launch_bounds__(256) void prep_kernel(
    const float* __restrict__ features,
    int4*        __restrict__ f8feat,
    int N)
{
    int i = blockIdx.x * blockDim.x + threadIdx.x;
    if (i >= N) return;
    const float2* r = (const float2*)(features + (size_t)i * NODELEN);
    float2 a0 = r[0], a1 = r[1], a2 = r[2], a3 = r[3], a4 = r[4];
    float v[NODELEN] = {a0.x, a0.y, a1.x, a1.y, a2.x, a2.y, a3.x, a3.y, a4.x, a4.y};
    f8feat[i] = pack_row_fp8(v);
}

// ---------------------------------------------------------------------------
// Kernel 1: hop-1 mean. 4 lanes/node, 8 batched gathers per lane, butterfly
// reduce, sub==0 lanes store 16 consecutive 16B rows per wave (full lines).
// min-waves=4 -> VGPR cap 128 so the 8 gathers stay in flight.
// ---------------------------------------------------------------------------
__global__ __launch_bounds__(256, 4) void hop1_kernel(
    const int4* __restrict__ f8feat,
    const int*  __restrict__ adj,
    int4*       __restrict__ f8h1,
    int N)
{
    int t = blockIdx.x * blockDim.x + threadIdx.x;
    int i = t >> 2, sub = t & 3;
    if (i >= N) return;                    // whole quads retire together

    const int4* arow = (const int4*)(adj + (size_t)i * DEG + sub * 8);
    int4 n0 = arow[0], n1 = arow[1];

    float s[NODELEN];
#pragma unroll
    for (int k = 0; k < NODELEN; ++k) s[k] = 0.0f;
    gather8_acc(s, f8feat, n0, n1);

#pragma unroll
    for (int k = 0; k < NODELEN; ++k) {
        s[k] += __shfl_xor(s[k], 1);
        s[k] += __shfl_xor(s[k], 2);
    }

    if (sub == 0) {
        const float inv = 1.0f / (float)DEG;
        float h[NODELEN];
        h[0] = 0.0f;
#pragma unroll
        for (int k = 1; k < NODELEN; ++k) h[k] = s[k] * inv;
        f8h1[i] = pack_row_fp8(h);
    }
}

// ---------------------------------------------------------------------------
// Kernel 2: hop-2 + MLP + coalesced stores. 256 threads / 64 nodes per block.
// Phase 2 is spread across all 4 waves (16 MLPs each) instead of wave 0 only.
// ---------------------------------------------------------------------------
__global__ __launch_bounds__(256, 4) void hop2_mlp_kernel(
    const float* __restrict__ features,
    const int*   __restrict__ adj,
    const int4*  __restrict__ f8h1,
    const float* __restrict__ We1, const float* __restrict__ be1,
    const float* __restrict__ We2, const float* __restrict__ be2,
    const float* __restrict__ We3, const float* __restrict__ be3,
    const float* __restrict__ Wd1, const float* __restrict__ bd1,
    const float* __restrict__ Wd2, const float* __restrict__ bd2,
    const float* __restrict__ Wd3, const float* __restrict__ bd3,
    float* __restrict__ out_enc,   // [N][5]
    float* __restrict__ out_dec,   // [N][20]
    float* __restrict__ out_emb,   // [N][20]
    int N)
{
    __shared__ float  s_agg[NPB][11];        // +1 pad breaks stride-10 conflicts
    __shared__ float4 s_feat4[NPB * 10 / 4]; // 64 rows x 40B, flat
    __shared__ float4 s_enc4[NPB * 5 / 4];   // 80
    __shared__ float4 s_dec4[NPB * 20 / 4];  // 320
    __shared__ float4 s_emb4[NPB * 20 / 4];  // 320

    const int tid  = threadIdx.x;
    const int base = blockIdx.x * NPB;
    const int nl   = tid >> 2, sub = tid & 3;
    const int i    = base + nl;
    const bool full = (base + NPB <= N);

    // stage this block's feature rows coalesced (2560B contiguous)
    if (full) {
        const float4* gf = (const float4*)(features + (size_t)base * NODELEN);
        if (tid < NPB * 10 / 4) s_feat4[tid] = gf[tid];
    } else {
        int cnt = (N - base) * NODELEN;
        for (int k = tid; k < cnt; k += 256)
            ((float*)s_feat4)[k] = features[(size_t)base * NODELEN + k];
    }

    // phase 1: gather (8 loads per lane in one latency window)
    float s[NODELEN];
#pragma unroll
    for (int k = 0; k < NODELEN; ++k) s[k] = 0.0f;
    if (i < N) {
        const int4* arow = (const int4*)(adj + (size_t)i * DEG + sub * 8);
        int4 n0 = arow[0], n1 = arow[1];
        gather8_acc(s, f8h1, n0, n1);
    }
#pragma unroll
    for (int k = 0; k < NODELEN; ++k) {
        s[k] += __shfl_xor(s[k], 1);
        s[k] += __shfl_xor(s[k], 2);
    }
    if (sub == 0 && i < N) {
#pragma unroll
        for (int k = 0; k < NODELEN; ++k) s_agg[nl][k] = s[k];
    }
    __syncthreads();

    // phase 2: each wave runs 16 MLPs on its first 16 lanes (4x parallel vs
    // wave0-only)
    {
        const int wid  = tid >> 6;          // wave id 0..3
        const int lane = tid & 63;
        if (lane < 16) {
            const int nl2  = wid * 16 + lane;   // node-local 0..63
            const int node = base + nl2;
            if (node < N) {
                const float inv = 1.0f / (float)DEG;
                const float* fr = (const float*)s_feat4 + nl2 * NODELEN;

                float emb[2 * NODELEN];
                emb[0] = 0.0f;
#pragma unroll
                for (int k = 1; k < NODELEN; ++k) emb[k] = fr[k];
                emb[NODELEN] = 0.0f;
#pragma unroll
                for (int k = 1; k < NODELEN; ++k) emb[NODELEN + k] = s_agg[nl2][k] * inv;

                float t1[15];
#pragma unroll
                for (int o = 0; o < 15; ++o) {
                    float acc = be1[o];
#pragma unroll
                    for (int k = 0; k < 20; ++k) acc = fmaf(We1[o * 20 + k], emb[k], acc);
                    t1[o] = fmaxf(acc, 0.0f);
                }
                float t2[10];
#pragma unroll
                for (int o = 0; o < 10; ++o) {
                    float acc = be2[o];
#pragma unroll
                    for (int k = 0; k < 15; ++k) acc = fmaf(We2[o * 15 + k], t1[k], acc);
                    t2[o] = fmaxf(acc, 0.0f);
                }
                float enc[5];
#pragma unroll
                for (int o = 0; o < 5; ++o) {
                    float acc = be3[o];
#pragma unroll
                    for (int k = 0; k < 10; ++k) acc = fmaf(We3[o * 10 + k], t2[k], acc);
                    enc[o] = acc;
                }
                float t3[10];
#pragma unroll
                for (int o = 0; o < 10; ++o) {
                    float acc = bd1[o];
#pragma unroll
                    for (int k = 0; k < 5; ++k) acc = fmaf(Wd1[o * 5 + k], enc[k], acc);
                    t3[o] = fmaxf(acc, 0.0f);
                }
                float t4[15];
#pragma unroll
                for (int o = 0; o < 15; ++o) {
                    float acc = bd2[o];
#pragma unroll
                    for (int k = 0; k < 10; ++k) acc = fmaf(Wd2[o * 10 + k], t3[k], acc);
                    t4[o] = fmaxf(acc, 0.0f);
                }
                float dec[20];
#pragma unroll
                for (int o = 0; o < 20; ++o) {
                    float acc = bd3[o];
#pragma unroll
                    for (int k = 0; k < 15; ++k) acc = fmaf(Wd3[o * 15 + k], t4[k], acc);
                    dec[o] = acc;
                }

                float* se = (float*)s_enc4;
#pragma unroll
                for (int k = 0; k < 5; ++k) se[nl2 * 5 + k] = enc[k];
                float* sd = (float*)s_dec4;
#pragma unroll
                for (int k = 0; k < 20; ++k) sd[nl2 * 20 + k] = dec[k];
                float* sm = (float*)s_emb4;
#pragma unroll
                for (int k = 0; k < 20; ++k) sm[nl2 * 20 + k] = emb[k];
            }
        }
    }
    __syncthreads();

    // phase 3: coalesced full-line stores
    if (full) {
        float4* gd = (float4*)(out_dec + (size_t)base * 20);
#pragma unroll
        for (int k = tid; k < NPB * 20 / 4; k += 256) gd[k] = s_dec4[k];
        float4* gm = (float4*)(out_emb + (size_t)base * 20);
#pragma unroll
        for (int k = tid; k < NPB * 20 / 4; k += 256) gm[k] = s_emb4[k];
        float4* ge = (float4*)(out_enc + (size_t)base * 5);
        if (tid < NPB * 5 / 4) ge[tid] = s_enc4[tid];
    } else {
        int cnt = N - base;
        for (int k = tid; k < cnt * 20; k += 256)
            out_dec[(size_t)base * 20 + k] = ((float*)s_dec4)[k];
        for (int k = tid; k < cnt * 20; k += 256)
            out_emb[(size_t)base * 20 + k] = ((float*)s_emb4)[k];
        for (int k = tid; k < cnt * 5; k += 256)
            out_enc[(size_t)base * 5 + k] = ((float*)s_enc4)[k];
    }
}

extern "C" void kernel_launch(void* const* d_in, const int* in_sizes, int n_in,
                              void* d_out, int out_size, void* d_ws, size_t ws_size,
                              hipStream_t stream)
{
    const float* features = (const float*)d_in[0];
    const int*   adj      = (const int*)  d_in[1];
    const float* We1 = (const float*)d_in[2];  const float* be1 = (const float*)d_in[3];
    const float* We2 = (const float*)d_in[4];  const float* be2 = (const float*)d_in[5];
    const float* We3 = (const float*)d_in[6];  const float* be3 = (const float*)d_in[7];
    const float* Wd1 = (const float*)d_in[8];  const float* bd1 = (const float*)d_in[9];
    const float* Wd2 = (const float*)d_in[10]; const float* bd2 = (const float*)d_in[11];
    const float* Wd3 = (const float*)d_in[12]; const float* bd3 = (const float*)d_in[13];

    const int N = in_sizes[0] / NODELEN;

    int4* f8feat = (int4*)d_ws;                           // N * 16 B = 3.2 MB
    int4* f8h1   = (int4*)((char*)d_ws + (size_t)N * 16); // N * 16 B = 3.2 MB

    float* out     = (float*)d_out;
    float* out_enc = out;                      // [N][5]
    float* out_dec = out + (size_t)N * 5;      // [N][20]
    float* out_emb = out + (size_t)N * 25;     // [N][20]

    const int threads = 256;

    hipLaunchKernelGGL(prep_kernel, dim3((N + 255) / 256), dim3(threads), 0, stream,
                       features, f8feat, N);
    hipLaunchKernelGGL(hop1_kernel, dim3((4 * N + 255) / 256), dim3(threads), 0, stream,
                       f8feat, adj, f8h1, N);
    hipLaunchKernelGGL(hop2_mlp_kernel, dim3((N + NPB - 1) / NPB), dim3(threads), 0, stream,
                       features, adj, f8h1,
                       We1, be1, We2, be2, We3, be3,
                       Wd1, bd1, Wd2, bd2, Wd3, bd3,
                       out_enc, out_dec, out_emb, N);
}